// Round 8
// baseline (379.009 us; speedup 1.0000x reference)
//
#include <hip/hip_runtime.h>
#include <stdint.h>

#define EPSF 1e-4f

typedef int v4i __attribute__((ext_vector_type(4)));

// ---------------- workspace layout (bytes) ----------------
#define OFF_SCALES 0            // 16 floats (slots 0..5 conv, 6..8 fc)
#define OFF_FOLD   1024         // folded BN params
#define OFF_W      32768        // B-fragment weights (MFMA lane order)
#define OFF_TF2    (OFF_W + 1548288)   // fc2 ternary [10][512]
#define OFF_ACT_A  2097152
#define OFF_ACT_B  60817408

static const int FOLD_OFF_H[8] = {0,128,256,512,768,1280,1792,2816};
__device__ __constant__ int FOLD_OFF_D[8] = {0,128,256,512,768,1280,1792,2816};

// per-layer B-frag prep tables: l0..5 = conv0..5, l6=fc0, l7=fc1
__device__ __constant__ int PREP_MODE[8] = {0,1,1,1,1,1,2,2};
__device__ __constant__ int PREP_CO[8]   = {64,64,128,128,256,256,512,512};
__device__ __constant__ int PREP_CI[8]   = {3,64,64,128,128,256,256,512};
__device__ __constant__ int PREP_KC[8]   = {1,1,1,2,2,4,1,1};
__device__ __constant__ int PREP_NB[8]   = {12288,36864,73728,147456,294912,589824,131072,262144};
__device__ __constant__ int PREP_OFF[8]  = {0,12288,49152,122880,270336,565248,1155072,1286144};

// ---------------- prep kernels ----------------
__global__ void zero_scales_k(float* s) { if (threadIdx.x < 16) s[threadIdx.x] = 0.f; }

struct AbsArgs { const float* w[9]; int n[9]; };
__global__ void absmax_all_k(AbsArgs a, float* scales) {
    __shared__ float red[256];
    int l = blockIdx.x >> 4;
    int sb = blockIdx.x & 15;
    const float* w = a.w[l];
    int n = a.n[l];
    float m = 0.f;
    for (int i = sb * 256 + threadIdx.x; i < n; i += 16 * 256)
        m = fmaxf(m, fabsf(w[i]));
    red[threadIdx.x] = m;
    __syncthreads();
    for (int s2 = 128; s2 > 0; s2 >>= 1) {
        if ((int)threadIdx.x < s2) red[threadIdx.x] = fmaxf(red[threadIdx.x], red[threadIdx.x + s2]);
        __syncthreads();
    }
    if (threadIdx.x == 0) atomicMax((unsigned int*)(scales + l), __float_as_uint(red[0]));
}

__global__ void tern_fc_k(const float* __restrict__ w, int n, const float* __restrict__ slot,
                          int8_t* __restrict__ t) {
    int i = blockIdx.x * blockDim.x + threadIdx.x;
    if (i >= n) return;
    float q = fminf(fmaxf(rintf(w[i] / slot[0]), -1.f), 1.f);
    t[i] = (int8_t)q;
}

// B-fragment prep: dest byte idx = ((s*COT + T)*64 + lane)*16 + jb
// lane = quad*16 + n ; k = s*64 + quad*16 + jb
// ct-interleaved co mapping (enables direct dword stores in the epilogue):
//   tile T = cg*4 + ct  ->  co = cg*64 + ct + 4*n
struct PrepArgs { const float* w[8]; };
__global__ void bprep_all_k(PrepArgs pa, const float* __restrict__ scales,
                            int8_t* __restrict__ dst) {
    int l = blockIdx.y;
    int idx = blockIdx.x * 256 + threadIdx.x;
    if (idx >= PREP_NB[l]) return;
    const float* w = pa.w[l];
    float s = scales[l];
    int jb = idx & 15;
    int lane = (idx >> 4) & 63;
    int fct = idx >> 10;
    int quad = lane >> 4, n = lane & 15;
    int COT = PREP_CO[l] >> 4;
    int ct = fct & (COT - 1);
    int st = fct >> (31 - __clz(COT));
    int co = (ct >> 2) * 64 + (ct & 3) + 4 * n;   // ct-interleaved
    float val;
    int md = PREP_MODE[l];
    if (md == 0) {
        // conv0, CI padded to 16: k = quad*16+jb -> dx=quad, ci=jb
        int ky = st, dx = quad, ci = jb;
        val = (dx < 3 && ci < 3) ? w[(co * 3 + ci) * 9 + ky * 3 + dx] : 0.f;
    } else if (md == 1) {
        int KC = PREP_KC[l], CI = PREP_CI[l];
        int kxy = st / KC, kc = st - kxy * KC;
        int ci = kc * 64 + quad * 16 + jb;
        val = w[(co * CI + ci) * 9 + kxy];
    } else {
        int CI = PREP_CI[l];
        int i = st * 64 + quad * 16 + jb;
        val = w[co * CI + i];
    }
    float q = fminf(fmaxf(rintf(val / s), -1.f), 1.f);
    dst[PREP_OFF[l] + idx] = (int8_t)q;
}

struct BnArgs { const float* g[8]; const float* b[8]; const float* m[8]; const float* v[8]; };
__global__ void bnfold_all_k(BnArgs ba, const float* __restrict__ scales,
                             float* __restrict__ fold) {
    int l = blockIdx.y;
    int i = blockIdx.x * 256 + threadIdx.x;
    int CO = PREP_CO[l];
    if (i >= CO) return;
    float sc = ba.g[l][i] / sqrtf(ba.v[l][i] + EPSF);
    float s_in = (l == 0) ? 0.0078125f : 1.0f;
    fold[FOLD_OFF_D[l] + i] = s_in * scales[l] * sc;
    fold[FOLD_OFF_D[l] + CO + i] = ba.b[l][i] - ba.m[l][i] * sc;
}

// input quant: NCHW float -> NHWC16 int8 (channels 3..15 zero)
__global__ void quant_in_k(const float* __restrict__ x, int4* __restrict__ o, int B) {
    int idx = blockIdx.x * blockDim.x + threadIdx.x;
    if (idx >= B * 1024) return;
    int p = idx & 1023;
    int b = idx >> 10;
    unsigned pk = 0;
#pragma unroll
    for (int c = 0; c < 3; ++c) {
        float q = rintf(x[((size_t)b * 3 + c) * 1024 + p] * 128.f);
        q = fminf(fmaxf(q, -127.f), 127.f);
        pk |= ((unsigned)((int)q & 0xff)) << (8 * c);
    }
    o[idx] = make_int4((int)pk, 0, 0, 0);
}

// ---------------- persistent MFMA implicit-GEMM conv/FC ----------------
// grid.y = co-group cg (64 co per block); grid.x*4 waves loop NITER pos-groups.
// All NSTEP B-tiles (4KB each) staged in LDS ONCE per block, single barrier,
// then a barrier-free pg-loop: per step prefetch-1 A (global dwordx4) and
// B (ds_read_b128) into alternate register buffers; sched_barrier(0) pins the
// prefetch above the 16*J MFMAs. Epilogue packs 4 consecutive co bytes into a
// dword and stores directly (no LDS transpose).
template<int CO, int NSTEP, int KC, int KXN, int CI, int IH, int IW, int OW,
         int NPOS1, int J, int NITER, int WPE>
__global__ __launch_bounds__(256, WPE) void mfconvP_k(
        const int8_t* __restrict__ act, const int8_t* __restrict__ bf,
        const float* __restrict__ fold, int8_t* __restrict__ out, int NPOS) {
    constexpr int NCT = 4;
    constexpr int COT = CO / 16;
    __shared__ __align__(16) int8_t lds[NSTEP * 4096];

    int lane = threadIdx.x & 63;
    int wid = threadIdx.x >> 6;
    int cg = blockIdx.y;
    int m = lane & 15, quad = lane >> 4;
    int PG = NPOS / (16 * J);
    int wstride = gridDim.x * 4;
    int pgBase = blockIdx.x * 4 + wid;

    // stage ALL B tiles for this cg (ct 0..3 contiguous per step)
#pragma unroll
    for (int s = 0; s < NSTEP; ++s)
        *(v4i*)&lds[s * 4096 + (int)threadIdx.x * 16] =
            *(const v4i*)(bf + ((size_t)(s * COT + cg * 4)) * 1024 + (int)threadIdx.x * 16);
    __syncthreads();

    auto ldB = [&](int s, v4i* dst) {
#pragma unroll
        for (int ct = 0; ct < NCT; ++ct)
            dst[ct] = *(const v4i*)&lds[s * 4096 + ct * 1024 + lane * 16];
    };

    float Af[NCT], Bf[NCT];
#pragma unroll
    for (int ct = 0; ct < NCT; ++ct) {
        int co = cg * 64 + ct + 4 * m;
        Af[ct] = fold[co];
        Bf[ct] = fold[CO + co];
    }

#pragma unroll 1
    for (int it = 0; it < NITER; ++it) {
        int pg = pgBase + it * wstride;
        if (pg >= PG) break;                      // wave-uniform
        int pos0 = pg * (16 * J);

        const int8_t* ab[J];
#pragma unroll
        for (int j = 0; j < J; ++j) {
            int pos = pos0 + j * 16 + m;
            int img = pos / NPOS1, p = pos - img * NPOS1;
            int oy = p / OW, ox = p - oy * OW;
            ab[j] = act + (size_t)((img * IH + oy) * IW + ox) * CI + quad * 16;
        }
        auto ldA = [&](int s, v4i* dst) {
            int kxy = s / KC, kc = s - kxy * KC;
            int ky = kxy / KXN, kx = kxy - ky * KXN;
            int off = (ky * IW + kx) * CI + kc * 64;
#pragma unroll
            for (int j = 0; j < J; ++j) dst[j] = *(const v4i*)(ab[j] + off);
        };

        v4i Ab[2][J], Bb[2][NCT];
        v4i acc[J][NCT] = {};
        ldA(0, Ab[0]);
        ldB(0, Bb[0]);
#pragma unroll
        for (int s = 0; s < NSTEP; ++s) {
            int cb = s & 1, nb = cb ^ 1;
            if (s + 1 < NSTEP) {
                ldA(s + 1, Ab[nb]);
                ldB(s + 1, Bb[nb]);
            }
            __builtin_amdgcn_sched_barrier(0);    // pin prefetch above MFMAs
#pragma unroll
            for (int j = 0; j < J; ++j)
#pragma unroll
                for (int ct = 0; ct < NCT; ++ct)
                    acc[j][ct] = __builtin_amdgcn_mfma_i32_16x16x64_i8(
                        Ab[cb][j], Bb[cb][ct], acc[j][ct], 0, 0, 0);
        }

        // epilogue: BN + 2-bit quant, pack 4 consecutive co bytes -> dword store
#pragma unroll
        for (int j = 0; j < J; ++j) {
#pragma unroll
            for (int r = 0; r < 4; ++r) {
                unsigned pk = 0;
#pragma unroll
                for (int ct = 0; ct < NCT; ++ct) {
                    float h = (float)acc[j][ct][r] * Af[ct] + Bf[ct];
                    int q = (int)fminf(fmaxf(rintf(h), -1.f), 1.f);
                    pk |= ((unsigned)(q & 0xff)) << (8 * ct);
                }
                *(int*)&out[(size_t)(pos0 + j * 16 + quad * 4 + r) * CO + cg * 64 + 4 * m] = (int)pk;
            }
        }
    }
}

// ---------------- chunked MFMA kernel (conv5 only: B too big for LDS) ----
template<int CO, int NSTEP, int KC, int KXN, int CI, int IH, int IW, int OW,
         int NPOS1, int J, int NCT, int COG>
__global__ __launch_bounds__(256, 3) void mfconv_k(
        const int8_t* __restrict__ act, const int8_t* __restrict__ bf,
        const float* __restrict__ fold, int8_t* __restrict__ out, int NPOS) {
    static_assert(NCT == 4, "epilogue packs 4 cotiles per dword");
    constexpr int COT = CO / 16;
    constexpr int CH = NSTEP < 9 ? NSTEP : 9;
    constexpr int NCHK = NSTEP / CH;
    __shared__ __align__(16) int8_t lds[CH * NCT * 1024];

    int lane = threadIdx.x & 63;
    int wid = threadIdx.x >> 6;
    int w = blockIdx.x * 4 + wid;
    int PG = NPOS / (16 * J);
    int pg = w % PG, cg = w / PG;
    int m = lane & 15, quad = lane >> 4;
    int pos0 = pg * (16 * J);

    const int8_t* ab[J];
#pragma unroll
    for (int j = 0; j < J; ++j) {
        int pos = pos0 + j * 16 + m;
        int img = pos / NPOS1, p = pos - img * NPOS1;
        int oy = p / OW, ox = p - oy * OW;
        ab[j] = act + (size_t)((img * IH + oy) * IW + ox) * CI + quad * 16;
    }

    auto ldA = [&](int s, v4i* dst) {
        int kxy = s / KC, kc = s - kxy * KC;
        int ky = kxy / KXN, kx = kxy - ky * KXN;
        int off = (ky * IW + kx) * CI + kc * 64;
#pragma unroll
        for (int j = 0; j < J; ++j) dst[j] = *(const v4i*)(ab[j] + off);
    };
    auto ldB = [&](int ls, v4i* dst) {
#pragma unroll
        for (int ct = 0; ct < NCT; ++ct)
            dst[ct] = *(const v4i*)&lds[(ls * NCT + ct) * 1024 + lane * 16];
    };

    v4i Ab[2][J], Bb[2][NCT];
    v4i acc[J][NCT] = {};

#pragma unroll
    for (int c = 0; c < NCHK; ++c) {
        int s0 = c * CH;
        __syncthreads();
#pragma unroll
        for (int ls = 0; ls < CH; ++ls) {
            const int8_t* src = bf + ((size_t)((s0 + ls) * COT) + cg * NCT) * 1024;
#pragma unroll
            for (int k = 0; k < NCT / 4; ++k)
                *(v4i*)&lds[ls * NCT * 1024 + (k * 256 + (int)threadIdx.x) * 16] =
                    *(const v4i*)(src + (k * 256 + (int)threadIdx.x) * 16);
        }
        __syncthreads();
        ldA(s0, Ab[0]);
        ldB(0, Bb[0]);
#pragma unroll
        for (int ls = 0; ls < CH; ++ls) {
            int cb = ls & 1, nb = cb ^ 1;
            if (ls + 1 < CH) {
                ldA(s0 + ls + 1, Ab[nb]);
                ldB(ls + 1, Bb[nb]);
            }
            __builtin_amdgcn_sched_barrier(0);
#pragma unroll
            for (int j = 0; j < J; ++j)
#pragma unroll
                for (int ct = 0; ct < NCT; ++ct)
                    acc[j][ct] = __builtin_amdgcn_mfma_i32_16x16x64_i8(
                        Ab[cb][j], Bb[cb][ct], acc[j][ct], 0, 0, 0);
        }
    }

    float Af[NCT], Bf[NCT];
#pragma unroll
    for (int ct = 0; ct < NCT; ++ct) {
        int co = cg * 64 + ct + 4 * m;
        Af[ct] = fold[co];
        Bf[ct] = fold[CO + co];
    }
#pragma unroll
    for (int j = 0; j < J; ++j) {
#pragma unroll
        for (int r = 0; r < 4; ++r) {
            unsigned pk = 0;
#pragma unroll
            for (int ct = 0; ct < NCT; ++ct) {
                float h = (float)acc[j][ct][r] * Af[ct] + Bf[ct];
                int q = (int)fminf(fmaxf(rintf(h), -1.f), 1.f);
                pk |= ((unsigned)(q & 0xff)) << (8 * ct);
            }
            *(int*)&out[(size_t)(pos0 + j * 16 + quad * 4 + r) * CO + cg * 64 + 4 * m] = (int)pk;
        }
    }
}

// ---------------- pool (int4: 16 channels per thread) ----------------
__global__ void pool_k(const int8_t* __restrict__ a, int8_t* __restrict__ o,
                       int B, int C, int IH, int IW, int OH, int OW) {
    int idx = blockIdx.x * blockDim.x + threadIdx.x;
    int c16n = C >> 4;
    int total = B * OH * OW * c16n;
    if (idx >= total) return;
    int c16 = idx % c16n;
    int t1 = idx / c16n;
    int ox = t1 % OW;
    int t2 = t1 / OW;
    int oy = t2 % OH;
    int b = t2 / OH;
    const int8_t* p = a + (((size_t)b * IH + 2 * oy) * IW + 2 * ox) * C + 16 * c16;
    int4 w0 = *(const int4*)p;
    int4 w1 = *(const int4*)(p + C);
    int4 w2 = *(const int4*)(p + (size_t)IW * C);
    int4 w3 = *(const int4*)(p + (size_t)IW * C + C);
    int4 r;
    const int* a0 = (const int*)&w0; const int* a1 = (const int*)&w1;
    const int* a2 = (const int*)&w2; const int* a3 = (const int*)&w3;
    int* rr = (int*)&r;
#pragma unroll
    for (int d = 0; d < 4; ++d) {
        unsigned v = 0;
#pragma unroll
        for (int k = 0; k < 4; ++k) {
            int x0 = (int)(int8_t)(a0[d] >> (8 * k));
            int x1 = (int)(int8_t)(a1[d] >> (8 * k));
            int x2 = (int)(int8_t)(a2[d] >> (8 * k));
            int x3 = (int)(int8_t)(a3[d] >> (8 * k));
            int mx = max(max(x0, x1), max(x2, x3));
            v |= ((unsigned)(mx & 0xff)) << (8 * k);
        }
        rr[d] = (int)v;
    }
    *(int4*)(o + (((size_t)b * OH + oy) * OW + ox) * C + 16 * c16) = r;
}

__device__ __forceinline__ int dot4(int a, int b, int c) {
#if __has_builtin(__builtin_amdgcn_sdot4)
    return __builtin_amdgcn_sdot4(a, b, c, false);
#else
    c += (int)(int8_t)(a) * (int)(int8_t)(b);
    c += (int)(int8_t)(a >> 8)  * (int)(int8_t)(b >> 8);
    c += (int)(int8_t)(a >> 16) * (int)(int8_t)(b >> 16);
    c += (int)(int8_t)(a >> 24) * (int)(int8_t)(b >> 24);
    return c;
#endif
}

// final FC + tensor norm -> float out (tiny: 1024x10x512)
__global__ void fc_out_k(const int8_t* __restrict__ a, const int8_t* __restrict__ t,
                         const float* __restrict__ slot,
                         const float* __restrict__ tw, const float* __restrict__ tb,
                         const float* __restrict__ tm, const float* __restrict__ tv,
                         float* __restrict__ out, int B, int I, int O) {
    int idx = blockIdx.x * blockDim.x + threadIdx.x;
    if (idx >= B * O) return;
    int o = idx % O;
    int b = idx / O;
    const int* ar = (const int*)(a + (size_t)b * I);
    const int* tr = (const int*)(t + (size_t)o * I);
    int acc = 0;
    for (int i = 0; i < (I >> 2); ++i) acc = dot4(ar[i], tr[i], acc);
    float sc = tw[0] / sqrtf(tv[0] + EPSF);
    out[idx] = ((float)acc * slot[0] - tm[0]) * sc + tb[0];
}

static inline unsigned cdiv(long long a, int b) { return (unsigned)((a + b - 1) / b); }

extern "C" void kernel_launch(void* const* d_in, const int* in_sizes, int n_in,
                              void* d_out, int out_size, void* d_ws, size_t ws_size,
                              hipStream_t stream) {
    const float* x = (const float*)d_in[0];
    const float* cw[6]; const float* bng[6]; const float* bnb[6];
    const float* bnm[6]; const float* bnv[6];
    for (int l = 0; l < 6; ++l) {
        cw[l]  = (const float*)d_in[1 + 5 * l + 0];
        bng[l] = (const float*)d_in[1 + 5 * l + 1];
        bnb[l] = (const float*)d_in[1 + 5 * l + 2];
        bnm[l] = (const float*)d_in[1 + 5 * l + 3];
        bnv[l] = (const float*)d_in[1 + 5 * l + 4];
    }
    const float* fw0 = (const float*)d_in[31];
    const float* fw1 = (const float*)d_in[32];
    const float* fw2 = (const float*)d_in[33];
    const float* fbn[2][4] = {
        { (const float*)d_in[34], (const float*)d_in[35], (const float*)d_in[36], (const float*)d_in[37] },
        { (const float*)d_in[38], (const float*)d_in[39], (const float*)d_in[40], (const float*)d_in[41] } };
    const float* tn_w = (const float*)d_in[42];
    const float* tn_b = (const float*)d_in[43];
    const float* tn_m = (const float*)d_in[44];
    const float* tn_v = (const float*)d_in[45];

    char* ws = (char*)d_ws;
    float* scales = (float*)(ws + OFF_SCALES);
    float* fold = (float*)(ws + OFF_FOLD);
    int8_t* bfw = (int8_t*)(ws + OFF_W);
    int8_t* tf2 = (int8_t*)(ws + OFF_TF2);
    int8_t* actA = (int8_t*)(ws + OFF_ACT_A);
    int8_t* actB = (int8_t*)(ws + OFF_ACT_B);

    const int B = in_sizes[0] / 3072;

    hipLaunchKernelGGL(zero_scales_k, dim3(1), dim3(16), 0, stream, scales);

    AbsArgs aa;
    aa.w[0]=cw[0]; aa.w[1]=cw[1]; aa.w[2]=cw[2]; aa.w[3]=cw[3]; aa.w[4]=cw[4]; aa.w[5]=cw[5];
    aa.w[6]=fw0; aa.w[7]=fw1; aa.w[8]=fw2;
    aa.n[0]=64*3*9; aa.n[1]=64*64*9; aa.n[2]=128*64*9; aa.n[3]=128*128*9;
    aa.n[4]=256*128*9; aa.n[5]=256*256*9; aa.n[6]=512*256; aa.n[7]=512*512; aa.n[8]=10*512;
    hipLaunchKernelGGL(absmax_all_k, dim3(144), dim3(256), 0, stream, aa, scales);

    hipLaunchKernelGGL(tern_fc_k, dim3(20), dim3(256), 0, stream, fw2, 5120, scales + 8, tf2);

    PrepArgs pp;
    pp.w[0]=cw[0]; pp.w[1]=cw[1]; pp.w[2]=cw[2]; pp.w[3]=cw[3]; pp.w[4]=cw[4]; pp.w[5]=cw[5];
    pp.w[6]=fw0; pp.w[7]=fw1;
    hipLaunchKernelGGL(bprep_all_k, dim3(2304, 8), dim3(256), 0, stream, pp, scales, bfw);

    BnArgs bb;
    for (int l = 0; l < 6; ++l) { bb.g[l]=bng[l]; bb.b[l]=bnb[l]; bb.m[l]=bnm[l]; bb.v[l]=bnv[l]; }
    for (int l = 0; l < 2; ++l) { bb.g[6+l]=fbn[l][0]; bb.b[6+l]=fbn[l][1]; bb.m[6+l]=fbn[l][2]; bb.v[6+l]=fbn[l][3]; }
    hipLaunchKernelGGL(bnfold_all_k, dim3(2, 8), dim3(256), 0, stream, bb, scales, fold);

    hipLaunchKernelGGL(quant_in_k, dim3(cdiv((long long)B * 1024, 256)), dim3(256), 0, stream,
                       x, (int4*)actA, B);

    // conv0: CI16(pad), 32->30, CO64; PG=14400, 720 blk x4 waves x5 iters
    hipLaunchKernelGGL((mfconvP_k<64, 3, 1, 1, 16, 32, 32, 30, 900, 4, 5, 3>),
                       dim3(720, 1), dim3(256), 0, stream, actA, bfw + 0, fold + FOLD_OFF_H[0], actB, B * 900);
    // conv1: CI64, 30->28, CO64; PG=12544, 784 blk x4 x4
    hipLaunchKernelGGL((mfconvP_k<64, 9, 1, 3, 64, 30, 30, 28, 784, 4, 4, 3>),
                       dim3(784, 1), dim3(256), 0, stream, actB, bfw + 12288, fold + FOLD_OFF_H[1], actA, B * 784);
    // pool 28->14 (64ch)
    hipLaunchKernelGGL(pool_k, dim3(cdiv((long long)B * 14 * 14 * 4, 256)), dim3(256), 0, stream,
                       actA, actB, B, 64, 28, 28, 14, 14);
    // conv2: CI64, 14->12, CO128; per-cg PG=2304, 288 blk x2cg x2 iters
    hipLaunchKernelGGL((mfconvP_k<128, 9, 1, 3, 64, 14, 14, 12, 144, 4, 2, 3>),
                       dim3(288, 2), dim3(256), 0, stream, actB, bfw + 49152, fold + FOLD_OFF_H[2], actA, B * 144);
    // conv3: CI128, 12->10, CO128; PG=1600, 200 blk x2cg x2 iters (72KB LDS)
    hipLaunchKernelGGL((mfconvP_k<128, 18, 2, 3, 128, 12, 12, 10, 100, 4, 2, 2>),
                       dim3(200, 2), dim3(256), 0, stream, actA, bfw + 122880, fold + FOLD_OFF_H[3], actB, B * 100);
    // pool 10->5 (128ch)
    hipLaunchKernelGGL(pool_k, dim3(cdiv((long long)B * 5 * 5 * 8, 256)), dim3(256), 0, stream,
                       actB, actA, B, 128, 10, 10, 5, 5);
    // conv4: CI128, 5->3, CO256; J=2, PG=288, 72 blk x4cg x1 (72KB LDS)
    hipLaunchKernelGGL((mfconvP_k<256, 18, 2, 3, 128, 5, 5, 3, 9, 2, 1, 2>),
                       dim3(72, 4), dim3(256), 0, stream, actA, bfw + 270336, fold + FOLD_OFF_H[4], actB, B * 9);
    // conv5 as FC: I=2304, O=256 — chunked path (B=144KB > LDS)
    {   int NPOS = B, PG = NPOS / 16, blks = (PG * 4) / 4;
        hipLaunchKernelGGL((mfconv_k<256, 36, 36, 1, 2304, 1, 1, 1, 1, 1, 4, 4>),
                           dim3(blks), dim3(256), 0, stream, actB, bfw + 565248, fold + FOLD_OFF_H[5], actA, NPOS); }
    // fc0: I=256, O=512; PG=64, 16 blk x8cg x1
    hipLaunchKernelGGL((mfconvP_k<512, 4, 4, 1, 256, 1, 1, 1, 1, 1, 1, 3>),
                       dim3(16, 8), dim3(256), 0, stream, actA, bfw + 1155072, fold + FOLD_OFF_H[6], actB, B);
    // fc1: I=512, O=512; PG=64, 16 blk x8cg x1
    hipLaunchKernelGGL((mfconvP_k<512, 8, 8, 1, 512, 1, 1, 1, 1, 1, 1, 3>),
                       dim3(16, 8), dim3(256), 0, stream, actB, bfw + 1286144, fold + FOLD_OFF_H[7], actA, B);
    // fc2 + tensor norm
    hipLaunchKernelGGL(fc_out_k, dim3(cdiv((long long)B * 10, 256)), dim3(256), 0, stream,
                       actA, tf2, scales + 8, tn_w, tn_b, tn_m, tn_v,
                       (float*)d_out, B, 512, 10);
}

// Round 9
// 368.137 us; speedup vs baseline: 1.0295x; 1.0295x over previous
//
#include <hip/hip_runtime.h>
#include <stdint.h>

#define EPSF 1e-4f

typedef int v4i __attribute__((ext_vector_type(4)));

// ---------------- workspace layout (bytes) ----------------
#define OFF_SCALES 0            // 16 floats (slots 0..5 conv, 6..8 fc)
#define OFF_FOLD   1024         // folded BN params
#define OFF_W      32768        // B-fragment weights (MFMA lane order)
#define OFF_TF2    (OFF_W + 1548288)   // fc2 ternary [10][512]
#define OFF_ACT_A  2097152
#define OFF_ACT_B  60817408

static const int FOLD_OFF_H[8] = {0,128,256,512,768,1280,1792,2816};
__device__ __constant__ int FOLD_OFF_D[8] = {0,128,256,512,768,1280,1792,2816};

// per-layer B-frag prep tables: l0..5 = conv0..5, l6=fc0, l7=fc1
__device__ __constant__ int PREP_MODE[8] = {0,1,1,1,1,1,2,2};
__device__ __constant__ int PREP_CO[8]   = {64,64,128,128,256,256,512,512};
__device__ __constant__ int PREP_CI[8]   = {3,64,64,128,128,256,256,512};
__device__ __constant__ int PREP_KC[8]   = {1,1,1,2,2,4,1,1};
__device__ __constant__ int PREP_NB[8]   = {12288,36864,73728,147456,294912,589824,131072,262144};
__device__ __constant__ int PREP_OFF[8]  = {0,12288,49152,122880,270336,565248,1155072,1286144};

// ---------------- prep kernels ----------------
__global__ void zero_scales_k(float* s) { if (threadIdx.x < 16) s[threadIdx.x] = 0.f; }

struct AbsArgs { const float* w[9]; int n[9]; };
__global__ void absmax_all_k(AbsArgs a, float* scales) {
    __shared__ float red[256];
    int l = blockIdx.x >> 4;
    int sb = blockIdx.x & 15;
    const float* w = a.w[l];
    int n = a.n[l];
    float m = 0.f;
    for (int i = sb * 256 + threadIdx.x; i < n; i += 16 * 256)
        m = fmaxf(m, fabsf(w[i]));
    red[threadIdx.x] = m;
    __syncthreads();
    for (int s2 = 128; s2 > 0; s2 >>= 1) {
        if ((int)threadIdx.x < s2) red[threadIdx.x] = fmaxf(red[threadIdx.x], red[threadIdx.x + s2]);
        __syncthreads();
    }
    if (threadIdx.x == 0) atomicMax((unsigned int*)(scales + l), __float_as_uint(red[0]));
}

__global__ void tern_fc_k(const float* __restrict__ w, int n, const float* __restrict__ slot,
                          int8_t* __restrict__ t) {
    int i = blockIdx.x * blockDim.x + threadIdx.x;
    if (i >= n) return;
    float q = fminf(fmaxf(rintf(w[i] / slot[0]), -1.f), 1.f);
    t[i] = (int8_t)q;
}

// B-fragment prep: dest byte idx = ((s*COT + T)*64 + lane)*16 + jb
// lane = quad*16 + n ; k = s*64 + quad*16 + jb
// ct-interleaved co mapping (enables direct dword stores in the epilogue):
//   tile T = cg*4 + ct  ->  co = cg*64 + ct + 4*n
struct PrepArgs { const float* w[8]; };
__global__ void bprep_all_k(PrepArgs pa, const float* __restrict__ scales,
                            int8_t* __restrict__ dst) {
    int l = blockIdx.y;
    int idx = blockIdx.x * 256 + threadIdx.x;
    if (idx >= PREP_NB[l]) return;
    const float* w = pa.w[l];
    float s = scales[l];
    int jb = idx & 15;
    int lane = (idx >> 4) & 63;
    int fct = idx >> 10;
    int quad = lane >> 4, n = lane & 15;
    int COT = PREP_CO[l] >> 4;
    int ct = fct & (COT - 1);
    int st = fct >> (31 - __clz(COT));
    int co = (ct >> 2) * 64 + (ct & 3) + 4 * n;   // ct-interleaved
    float val;
    int md = PREP_MODE[l];
    if (md == 0) {
        // conv0, CI padded to 16: k = quad*16+jb -> dx=quad, ci=jb
        int ky = st, dx = quad, ci = jb;
        val = (dx < 3 && ci < 3) ? w[(co * 3 + ci) * 9 + ky * 3 + dx] : 0.f;
    } else if (md == 1) {
        int KC = PREP_KC[l], CI = PREP_CI[l];
        int kxy = st / KC, kc = st - kxy * KC;
        int ci = kc * 64 + quad * 16 + jb;
        val = w[(co * CI + ci) * 9 + kxy];
    } else {
        int CI = PREP_CI[l];
        int i = st * 64 + quad * 16 + jb;
        val = w[co * CI + i];
    }
    float q = fminf(fmaxf(rintf(val / s), -1.f), 1.f);
    dst[PREP_OFF[l] + idx] = (int8_t)q;
}

struct BnArgs { const float* g[8]; const float* b[8]; const float* m[8]; const float* v[8]; };
__global__ void bnfold_all_k(BnArgs ba, const float* __restrict__ scales,
                             float* __restrict__ fold) {
    int l = blockIdx.y;
    int i = blockIdx.x * 256 + threadIdx.x;
    int CO = PREP_CO[l];
    if (i >= CO) return;
    float sc = ba.g[l][i] / sqrtf(ba.v[l][i] + EPSF);
    float s_in = (l == 0) ? 0.0078125f : 1.0f;
    fold[FOLD_OFF_D[l] + i] = s_in * scales[l] * sc;
    fold[FOLD_OFF_D[l] + CO + i] = ba.b[l][i] - ba.m[l][i] * sc;
}

// input quant: NCHW float -> NHWC16 int8 (channels 3..15 zero)
__global__ void quant_in_k(const float* __restrict__ x, int4* __restrict__ o, int B) {
    int idx = blockIdx.x * blockDim.x + threadIdx.x;
    if (idx >= B * 1024) return;
    int p = idx & 1023;
    int b = idx >> 10;
    unsigned pk = 0;
#pragma unroll
    for (int c = 0; c < 3; ++c) {
        float q = rintf(x[((size_t)b * 3 + c) * 1024 + p] * 128.f);
        q = fminf(fmaxf(q, -127.f), 127.f);
        pk |= ((unsigned)((int)q & 0xff)) << (8 * c);
    }
    o[idx] = make_int4((int)pk, 0, 0, 0);
}

// ---------------- MFMA implicit-GEMM conv/FC ----------------
// A-frag: lane m=lane&15 (position), quad=lane>>4: 16B global load (coalesced).
// B-frag: block-uniform cg -> staged into LDS in chunks of CH steps,
//   consumed via ds_read_b128 (lane*16: 2-way bank alias = free).
// K-loop pipeline (R9): A uses a 3-deep register rotation (consume A[s%3],
//   prefetch A[(s+2)%3]) -> prefetch distance 2 (covers L2 latency) and WAR
//   distance >= 1 full MFMA group so the compiler cannot collapse the
//   buffers (R5-R8: VGPR=68..84 proved 2-deep buffers were collapsed).
//   B uses a 2-deep rotation (LDS latency ~120cyc needs only distance 1).
// C/D: col=lane&15, row=quad*4+reg. ct-interleaved B (co = cg*64+ct+4m):
//   pack 4 consecutive co bytes per dword, store directly. No LDS transpose.
template<int CO, int NSTEP, int KC, int KXN, int CI, int IH, int IW, int OW,
         int NPOS1, int J, int NCT, int COG>
__global__ __launch_bounds__(256, 3) void mfconv_k(
        const int8_t* __restrict__ act, const int8_t* __restrict__ bf,
        const float* __restrict__ fold, int8_t* __restrict__ out, int NPOS) {
    static_assert(NCT == 4, "epilogue packs 4 cotiles per dword");
    constexpr int COT = CO / 16;
    constexpr int CH = NSTEP < 9 ? NSTEP : 9;     // steps per LDS chunk
    constexpr int NCHK = NSTEP / CH;              // all configs: NSTEP % CH == 0
    __shared__ __align__(16) int8_t lds[CH * NCT * 1024];

    int lane = threadIdx.x & 63;
    int wid = threadIdx.x >> 6;
    int w = blockIdx.x * 4 + wid;                 // grid exact: no tail waves
    int PG = NPOS / (16 * J);
    int pg = w % PG, cg = w / PG;
    int m = lane & 15, quad = lane >> 4;
    int pos0 = pg * (16 * J);

    const int8_t* ab[J];
#pragma unroll
    for (int j = 0; j < J; ++j) {
        int pos = pos0 + j * 16 + m;
        int img = pos / NPOS1, p = pos - img * NPOS1;
        int oy = p / OW, ox = p - oy * OW;
        ab[j] = act + (size_t)((img * IH + oy) * IW + ox) * CI + quad * 16;
    }

    auto ldA = [&](int s, v4i (&dst)[J]) {
        int kxy = s / KC, kc = s - kxy * KC;
        int ky = kxy / KXN, kx = kxy - ky * KXN;
        int off = (ky * IW + kx) * CI + kc * 64;
#pragma unroll
        for (int j = 0; j < J; ++j) dst[j] = *(const v4i*)(ab[j] + off);
    };
    auto ldB = [&](int ls, v4i (&dst)[NCT]) {
#pragma unroll
        for (int ct = 0; ct < NCT; ++ct)
            dst[ct] = *(const v4i*)&lds[(ls * NCT + ct) * 1024 + lane * 16];
    };

    v4i A0[J], A1[J], A2[J];          // 3-deep A rotation
    v4i B0[NCT], B1[NCT];             // 2-deep B rotation
    v4i acc[J][NCT] = {};

#pragma unroll
    for (int c = 0; c < NCHK; ++c) {
        int s0 = c * CH;
        __syncthreads();                          // prior chunk fully consumed
        // cooperative B staging: CH steps x NCT tiles (contiguous per step)
#pragma unroll
        for (int ls = 0; ls < CH; ++ls) {
            const int8_t* src = bf + ((size_t)((s0 + ls) * COT) + cg * NCT) * 1024;
            *(v4i*)&lds[ls * NCT * 1024 + (int)threadIdx.x * 16] =
                *(const v4i*)(src + (int)threadIdx.x * 16);
        }
        __syncthreads();
        // pipeline prologue: A distance-2, B distance-1
        ldA(s0 + 0, A0);
        if (CH > 1) ldA(s0 + 1, A1);
        ldB(0, B0);
#pragma unroll
        for (int ls = 0; ls < CH; ++ls) {
            // prefetch next-next A into the buffer 2 steps ahead
            if (ls + 2 < CH) {
                if ((ls + 2) % 3 == 0) ldA(s0 + ls + 2, A0);
                else if ((ls + 2) % 3 == 1) ldA(s0 + ls + 2, A1);
                else ldA(s0 + ls + 2, A2);
            }
            if (ls + 1 < CH) {
                if ((ls + 1) & 1) ldB(ls + 1, B1);
                else ldB(ls + 1, B0);
            }
            __builtin_amdgcn_sched_barrier(0);    // pin prefetch above MFMAs
#pragma unroll
            for (int j = 0; j < J; ++j)
#pragma unroll
                for (int ct = 0; ct < NCT; ++ct) {
                    const v4i& Av = (ls % 3 == 0) ? A0[j] : (ls % 3 == 1) ? A1[j] : A2[j];
                    const v4i& Bv = (ls & 1) ? B1[ct] : B0[ct];
                    acc[j][ct] = __builtin_amdgcn_mfma_i32_16x16x64_i8(Av, Bv, acc[j][ct], 0, 0, 0);
                }
        }
    }

    // epilogue: BN + 2-bit quant, pack 4 consecutive co bytes -> dword store
    float Af[NCT], Bf[NCT];
#pragma unroll
    for (int ct = 0; ct < NCT; ++ct) {
        int co = cg * 64 + ct + 4 * m;
        Af[ct] = fold[co];
        Bf[ct] = fold[CO + co];
    }
#pragma unroll
    for (int j = 0; j < J; ++j) {
#pragma unroll
        for (int r = 0; r < 4; ++r) {
            unsigned pk = 0;
#pragma unroll
            for (int ct = 0; ct < NCT; ++ct) {
                float h = (float)acc[j][ct][r] * Af[ct] + Bf[ct];
                int q = (int)fminf(fmaxf(rintf(h), -1.f), 1.f);
                pk |= ((unsigned)(q & 0xff)) << (8 * ct);
            }
            *(int*)&out[(size_t)(pos0 + j * 16 + quad * 4 + r) * CO + cg * 64 + 4 * m] = (int)pk;
        }
    }
}

// ---------------- pool (int4: 16 channels per thread) ----------------
__global__ void pool_k(const int8_t* __restrict__ a, int8_t* __restrict__ o,
                       int B, int C, int IH, int IW, int OH, int OW) {
    int idx = blockIdx.x * blockDim.x + threadIdx.x;
    int c16n = C >> 4;
    int total = B * OH * OW * c16n;
    if (idx >= total) return;
    int c16 = idx % c16n;
    int t1 = idx / c16n;
    int ox = t1 % OW;
    int t2 = t1 / OW;
    int oy = t2 % OH;
    int b = t2 / OH;
    const int8_t* p = a + (((size_t)b * IH + 2 * oy) * IW + 2 * ox) * C + 16 * c16;
    int4 w0 = *(const int4*)p;
    int4 w1 = *(const int4*)(p + C);
    int4 w2 = *(const int4*)(p + (size_t)IW * C);
    int4 w3 = *(const int4*)(p + (size_t)IW * C + C);
    int4 r;
    const int* a0 = (const int*)&w0; const int* a1 = (const int*)&w1;
    const int* a2 = (const int*)&w2; const int* a3 = (const int*)&w3;
    int* rr = (int*)&r;
#pragma unroll
    for (int d = 0; d < 4; ++d) {
        unsigned v = 0;
#pragma unroll
        for (int k = 0; k < 4; ++k) {
            int x0 = (int)(int8_t)(a0[d] >> (8 * k));
            int x1 = (int)(int8_t)(a1[d] >> (8 * k));
            int x2 = (int)(int8_t)(a2[d] >> (8 * k));
            int x3 = (int)(int8_t)(a3[d] >> (8 * k));
            int mx = max(max(x0, x1), max(x2, x3));
            v |= ((unsigned)(mx & 0xff)) << (8 * k);
        }
        rr[d] = (int)v;
    }
    *(int4*)(o + (((size_t)b * OH + oy) * OW + ox) * C + 16 * c16) = r;
}

__device__ __forceinline__ int dot4(int a, int b, int c) {
#if __has_builtin(__builtin_amdgcn_sdot4)
    return __builtin_amdgcn_sdot4(a, b, c, false);
#else
    c += (int)(int8_t)(a) * (int)(int8_t)(b);
    c += (int)(int8_t)(a >> 8)  * (int)(int8_t)(b >> 8);
    c += (int)(int8_t)(a >> 16) * (int)(int8_t)(b >> 16);
    c += (int)(int8_t)(a >> 24) * (int)(int8_t)(b >> 24);
    return c;
#endif
}

// final FC + tensor norm -> float out (tiny: 1024x10x512)
__global__ void fc_out_k(const int8_t* __restrict__ a, const int8_t* __restrict__ t,
                         const float* __restrict__ slot,
                         const float* __restrict__ tw, const float* __restrict__ tb,
                         const float* __restrict__ tm, const float* __restrict__ tv,
                         float* __restrict__ out, int B, int I, int O) {
    int idx = blockIdx.x * blockDim.x + threadIdx.x;
    if (idx >= B * O) return;
    int o = idx % O;
    int b = idx / O;
    const int* ar = (const int*)(a + (size_t)b * I);
    const int* tr = (const int*)(t + (size_t)o * I);
    int acc = 0;
    for (int i = 0; i < (I >> 2); ++i) acc = dot4(ar[i], tr[i], acc);
    float sc = tw[0] / sqrtf(tv[0] + EPSF);
    out[idx] = ((float)acc * slot[0] - tm[0]) * sc + tb[0];
}

static inline unsigned cdiv(long long a, int b) { return (unsigned)((a + b - 1) / b); }

extern "C" void kernel_launch(void* const* d_in, const int* in_sizes, int n_in,
                              void* d_out, int out_size, void* d_ws, size_t ws_size,
                              hipStream_t stream) {
    const float* x = (const float*)d_in[0];
    const float* cw[6]; const float* bng[6]; const float* bnb[6];
    const float* bnm[6]; const float* bnv[6];
    for (int l = 0; l < 6; ++l) {
        cw[l]  = (const float*)d_in[1 + 5 * l + 0];
        bng[l] = (const float*)d_in[1 + 5 * l + 1];
        bnb[l] = (const float*)d_in[1 + 5 * l + 2];
        bnm[l] = (const float*)d_in[1 + 5 * l + 3];
        bnv[l] = (const float*)d_in[1 + 5 * l + 4];
    }
    const float* fw0 = (const float*)d_in[31];
    const float* fw1 = (const float*)d_in[32];
    const float* fw2 = (const float*)d_in[33];
    const float* fbn[2][4] = {
        { (const float*)d_in[34], (const float*)d_in[35], (const float*)d_in[36], (const float*)d_in[37] },
        { (const float*)d_in[38], (const float*)d_in[39], (const float*)d_in[40], (const float*)d_in[41] } };
    const float* tn_w = (const float*)d_in[42];
    const float* tn_b = (const float*)d_in[43];
    const float* tn_m = (const float*)d_in[44];
    const float* tn_v = (const float*)d_in[45];

    char* ws = (char*)d_ws;
    float* scales = (float*)(ws + OFF_SCALES);
    float* fold = (float*)(ws + OFF_FOLD);
    int8_t* bfw = (int8_t*)(ws + OFF_W);
    int8_t* tf2 = (int8_t*)(ws + OFF_TF2);
    int8_t* actA = (int8_t*)(ws + OFF_ACT_A);
    int8_t* actB = (int8_t*)(ws + OFF_ACT_B);

    const int B = in_sizes[0] / 3072;

    hipLaunchKernelGGL(zero_scales_k, dim3(1), dim3(16), 0, stream, scales);

    AbsArgs aa;
    aa.w[0]=cw[0]; aa.w[1]=cw[1]; aa.w[2]=cw[2]; aa.w[3]=cw[3]; aa.w[4]=cw[4]; aa.w[5]=cw[5];
    aa.w[6]=fw0; aa.w[7]=fw1; aa.w[8]=fw2;
    aa.n[0]=64*3*9; aa.n[1]=64*64*9; aa.n[2]=128*64*9; aa.n[3]=128*128*9;
    aa.n[4]=256*128*9; aa.n[5]=256*256*9; aa.n[6]=512*256; aa.n[7]=512*512; aa.n[8]=10*512;
    hipLaunchKernelGGL(absmax_all_k, dim3(144), dim3(256), 0, stream, aa, scales);

    hipLaunchKernelGGL(tern_fc_k, dim3(20), dim3(256), 0, stream, fw2, 5120, scales + 8, tf2);

    PrepArgs pp;
    pp.w[0]=cw[0]; pp.w[1]=cw[1]; pp.w[2]=cw[2]; pp.w[3]=cw[3]; pp.w[4]=cw[4]; pp.w[5]=cw[5];
    pp.w[6]=fw0; pp.w[7]=fw1;
    hipLaunchKernelGGL(bprep_all_k, dim3(2304, 8), dim3(256), 0, stream, pp, scales, bfw);

    BnArgs bb;
    for (int l = 0; l < 6; ++l) { bb.g[l]=bng[l]; bb.b[l]=bnb[l]; bb.m[l]=bnm[l]; bb.v[l]=bnv[l]; }
    for (int l = 0; l < 2; ++l) { bb.g[6+l]=fbn[l][0]; bb.b[6+l]=fbn[l][1]; bb.m[6+l]=fbn[l][2]; bb.v[6+l]=fbn[l][3]; }
    hipLaunchKernelGGL(bnfold_all_k, dim3(2, 8), dim3(256), 0, stream, bb, scales, fold);

    hipLaunchKernelGGL(quant_in_k, dim3(cdiv((long long)B * 1024, 256)), dim3(256), 0, stream,
                       x, (int4*)actA, B);

    // conv0: CI16(pad), 32->30, CO64, NSTEP=3 (ky), K=64 covers dx0..3 x ci
    {   int NPOS = B * 900, PG = NPOS / 64, blks = (PG * 1) / 4;
        hipLaunchKernelGGL((mfconv_k<64, 3, 1, 1, 16, 32, 32, 30, 900, 4, 4, 1>),
                           dim3(blks), dim3(256), 0, stream, actA, bfw + 0, fold + FOLD_OFF_H[0], actB, NPOS); }
    // conv1: CI64, 30->28, CO64
    {   int NPOS = B * 784, PG = NPOS / 64, blks = (PG * 1) / 4;
        hipLaunchKernelGGL((mfconv_k<64, 9, 1, 3, 64, 30, 30, 28, 784, 4, 4, 1>),
                           dim3(blks), dim3(256), 0, stream, actB, bfw + 12288, fold + FOLD_OFF_H[1], actA, NPOS); }
    // pool 28->14 (64ch)
    hipLaunchKernelGGL(pool_k, dim3(cdiv((long long)B * 14 * 14 * 4, 256)), dim3(256), 0, stream,
                       actA, actB, B, 64, 28, 28, 14, 14);
    // conv2: CI64, 14->12, CO128
    {   int NPOS = B * 144, PG = NPOS / 64, blks = (PG * 2) / 4;
        hipLaunchKernelGGL((mfconv_k<128, 9, 1, 3, 64, 14, 14, 12, 144, 4, 4, 2>),
                           dim3(blks), dim3(256), 0, stream, actB, bfw + 49152, fold + FOLD_OFF_H[2], actA, NPOS); }
    // conv3: CI128, 12->10, CO128
    {   int NPOS = B * 100, PG = NPOS / 64, blks = (PG * 2) / 4;
        hipLaunchKernelGGL((mfconv_k<128, 18, 2, 3, 128, 12, 12, 10, 100, 4, 4, 2>),
                           dim3(blks), dim3(256), 0, stream, actA, bfw + 122880, fold + FOLD_OFF_H[3], actB, NPOS); }
    // pool 10->5 (128ch)
    hipLaunchKernelGGL(pool_k, dim3(cdiv((long long)B * 5 * 5 * 8, 256)), dim3(256), 0, stream,
                       actB, actA, B, 128, 10, 10, 5, 5);
    // conv4: CI128, 5->3, CO256
    {   int NPOS = B * 9, PG = NPOS / 16, blks = (PG * 4) / 4;
        hipLaunchKernelGGL((mfconv_k<256, 18, 2, 3, 128, 5, 5, 3, 9, 1, 4, 4>),
                           dim3(blks), dim3(256), 0, stream, actA, bfw + 270336, fold + FOLD_OFF_H[4], actB, NPOS); }
    // conv5 as FC: I=2304, O=256
    {   int NPOS = B, PG = NPOS / 16, blks = (PG * 4) / 4;
        hipLaunchKernelGGL((mfconv_k<256, 36, 36, 1, 2304, 1, 1, 1, 1, 1, 4, 4>),
                           dim3(blks), dim3(256), 0, stream, actB, bfw + 565248, fold + FOLD_OFF_H[5], actA, NPOS); }
    // fc0: I=256, O=512
    {   int NPOS = B, PG = NPOS / 16, blks = (PG * 8) / 4;
        hipLaunchKernelGGL((mfconv_k<512, 4, 4, 1, 256, 1, 1, 1, 1, 1, 4, 8>),
                           dim3(blks), dim3(256), 0, stream, actA, bfw + 1155072, fold + FOLD_OFF_H[6], actB, NPOS); }
    // fc1: I=512, O=512
    {   int NPOS = B, PG = NPOS / 16, blks = (PG * 8) / 4;
        hipLaunchKernelGGL((mfconv_k<512, 8, 8, 1, 512, 1, 1, 1, 1, 1, 4, 8>),
                           dim3(blks), dim3(256), 0, stream, actB, bfw + 1286144, fold + FOLD_OFF_H[7], actA, NPOS); }
    // fc2 + tensor norm
    hipLaunchKernelGGL(fc_out_k, dim3(cdiv((long long)B * 10, 256)), dim3(256), 0, stream,
                       actA, tf2, scales + 8, tn_w, tn_b, tn_m, tn_v,
                       (float*)d_out, B, 512, 10);
}